// Round 1
// baseline (97.436 us; speedup 1.0000x reference)
//
#include <hip/hip_runtime.h>
#include <math.h>

// Problem geometry (fixed by the reference):
#define N_    32
#define C_    64
#define HW_   16384            // 128*128
#define PLANES (N_ * C_)       // 2048 planes of HW_ floats
#define F4PP  4096             // float4 per plane
#define NCHUNK 8               // 4 samples per chunk

// ws layout (bytes):
//   0    : u32 minEnc[32 + 512]   (memset 0xFF -> encoded +inf)
//   2176 : u32 maxEnc[32 + 512]   (memset 0x00 -> encoded -inf)
//   4352 : double chSum[64]       (memset 0x00)
//   4864 : float P[258]  P[0]=scale P[1]=zp P[2+c]=scale_c P[66+c]=qw
//                        P[130+c]=qb P[194+c]=mean
//   8192 : u8 qcache[33554432]    (optional, if ws_size permits)
#define OFF_MAXENC 2176
#define OFF_CHSUM  4352
#define OFF_P      4864
#define OFF_QC     8192

// ---- sortable-uint encoding for float atomics (non-NaN) ----
__device__ __forceinline__ unsigned encf(float f) {
    unsigned u = __float_as_uint(f);
    return (u & 0x80000000u) ? ~u : (u | 0x80000000u);
}
__device__ __forceinline__ float decf(unsigned u) {
    return __uint_as_float((u & 0x80000000u) ? (u & 0x7FFFFFFFu) : ~u);
}

// Faithful _quantize forward (scale>0 path; scale==0 guarded by caller).
__device__ __forceinline__ float quantv(float x, float scale, float zp) {
    float q = rintf(x / scale + zp);          // jnp.round = half-to-even
    q = fminf(fmaxf(q, 0.f), 255.f);
    return (q - zp) * scale;
}

// ---------- pass 1: per-sample & per-(chunk,channel) min/max of raw x ----------
__global__ void k_pass1(const float* __restrict__ x,
                        unsigned* __restrict__ minEnc,
                        unsigned* __restrict__ maxEnc) {
    const int p = blockIdx.x;          // plane = (n, c)
    const int n = p >> 6, c = p & 63;
    const float4* xp = (const float4*)x + (size_t)p * F4PP;
    float lmin = INFINITY, lmax = -INFINITY;
#pragma unroll
    for (int i = 0; i < 16; ++i) {
        float4 v = xp[threadIdx.x + i * 256];
        lmin = fminf(lmin, fminf(fminf(v.x, v.y), fminf(v.z, v.w)));
        lmax = fmaxf(lmax, fmaxf(fmaxf(v.x, v.y), fmaxf(v.z, v.w)));
    }
    // wave reduce (64 lanes)
    for (int o = 32; o; o >>= 1) {
        lmin = fminf(lmin, __shfl_xor(lmin, o));
        lmax = fmaxf(lmax, __shfl_xor(lmax, o));
    }
    __shared__ float smin[4], smax[4];
    const int wid = threadIdx.x >> 6;
    if ((threadIdx.x & 63) == 0) { smin[wid] = lmin; smax[wid] = lmax; }
    __syncthreads();
    if (threadIdx.x == 0) {
        float bmin = fminf(fminf(smin[0], smin[1]), fminf(smin[2], smin[3]));
        float bmax = fmaxf(fmaxf(smax[0], smax[1]), fmaxf(smax[2], smax[3]));
        atomicMin(&minEnc[n], encf(bmin));
        atomicMax(&maxEnc[n], encf(bmax));
        const int kc = 32 + (n >> 2) * 64 + c;
        atomicMin(&minEnc[kc], encf(bmin));
        atomicMax(&maxEnc[kc], encf(bmax));
    }
}

// ---------- params: scale/zp, per-channel scale_c (monotonicity), qw, qb ----------
__global__ void k_params(const unsigned* __restrict__ minEnc,
                         const unsigned* __restrict__ maxEnc,
                         const float* __restrict__ w,
                         const float* __restrict__ b,
                         float* __restrict__ P) {
    __shared__ float s_scale, s_zp;
    const int c = threadIdx.x;   // 64 threads = 1 wave
    if (c == 0) {
        double smin = 0.0, smax = 0.0;
        for (int i = 0; i < N_; ++i) {
            smin += (double)decf(minEnc[i]);
            smax += (double)decf(maxEnc[i]);
        }
        float min_v = (float)(smin / N_), max_v = (float)(smax / N_);
        float scale = (max_v - min_v) / 255.f;
        if (scale == 0.f) scale = 1.f;
        float zp = truncf(fminf(fmaxf(-min_v / scale, 0.f), 255.f));
        s_scale = scale; s_zp = zp;
        P[0] = scale; P[1] = zp;
    }
    __syncthreads();
    const float scale = s_scale, zp = s_zp;

    // per-channel scale from chunk ranges of xq = f(x): monotone, so use x stats
    const float cf = (float)(0.5 * 0.35 * (1.0 + sqrt(M_PI * log(4.0)))
                             / sqrt(2.0 * log(65536.0)));
    float s = 0.f;
    for (int k = 0; k < NCHUNK; ++k) {
        float xmin = decf(minEnc[32 + k * 64 + c]);
        float xmax = decf(maxEnc[32 + k * 64 + c]);
        s += (quantv(xmax, scale, zp) - quantv(xmin, scale, zp)) * cf;
    }
    float mean_topk = s / 8.f;
    P[2 + c] = 1.f / (mean_topk + 1e-7f);

    // qweight: min/max over 64 weights via wave reduce
    float wv = w[c];
    float wmin = wv, wmax = wv;
    for (int o = 32; o; o >>= 1) {
        wmin = fminf(wmin, __shfl_xor(wmin, o));
        wmax = fmaxf(wmax, __shfl_xor(wmax, o));
    }
    float wscale = (wmax - wmin) / 255.f;
    if (wscale == 0.f) wscale = 1.f;
    float wzp = truncf(fminf(fmaxf(-wmin / wscale, 0.f), 255.f));
    P[66 + c] = quantv(wv, wscale, wzp);

    // qbias: min=max=mean(bias) -> scale collapses to 1
    float bv = b[c];
    float bs = bv;
    for (int o = 32; o; o >>= 1) bs += __shfl_xor(bs, o);
    float bmm = bs / 64.f;
    float bzp = truncf(fminf(fmaxf(-bmm, 0.f), 255.f));
    P[130 + c] = fminf(fmaxf(rintf(bv + bzp), 0.f), 255.f) - bzp;
}

// ---------- pass 2: per-channel sum of xq (+ optional u8 q cache) ----------
template <bool WRITEQ>
__global__ void k_pass2(const float* __restrict__ x,
                        const float* __restrict__ P,
                        double* __restrict__ chSum,
                        unsigned char* __restrict__ qc) {
    const int p = blockIdx.x, c = p & 63;
    const float scale = P[0], zp = P[1];
    const float4* xp = (const float4*)x + (size_t)p * F4PP;
    uchar4* qp = WRITEQ ? ((uchar4*)qc + (size_t)p * F4PP) : nullptr;
    float fsum = 0.f;   // sum of (q - zp): exact small integers in fp32
#pragma unroll
    for (int i = 0; i < 16; ++i) {
        const int idx = threadIdx.x + i * 256;
        float4 v = xp[idx];
        float q0 = fminf(fmaxf(rintf(v.x / scale + zp), 0.f), 255.f);
        float q1 = fminf(fmaxf(rintf(v.y / scale + zp), 0.f), 255.f);
        float q2 = fminf(fmaxf(rintf(v.z / scale + zp), 0.f), 255.f);
        float q3 = fminf(fmaxf(rintf(v.w / scale + zp), 0.f), 255.f);
        fsum += (q0 - zp) + (q1 - zp) + (q2 - zp) + (q3 - zp);
        if (WRITEQ) {
            uchar4 u;
            u.x = (unsigned char)q0; u.y = (unsigned char)q1;
            u.z = (unsigned char)q2; u.w = (unsigned char)q3;
            qp[idx] = u;
        }
    }
    double acc = (double)fsum * (double)scale;   // xq sum for this thread
    for (int o = 32; o; o >>= 1) acc += __shfl_xor(acc, o);
    __shared__ double sd[4];
    const int wid = threadIdx.x >> 6;
    if ((threadIdx.x & 63) == 0) sd[wid] = acc;
    __syncthreads();
    if (threadIdx.x == 0)
        atomicAdd(&chSum[c], sd[0] + sd[1] + sd[2] + sd[3]);
}

// ---------- finalize: mean[c] ----------
__global__ void k_finalize(const double* __restrict__ chSum, float* __restrict__ P) {
    const int c = threadIdx.x;
    P[194 + c] = (float)(chSum[c] * (1.0 / (double)(N_ * HW_)));
}

// ---------- pass 3: out = (xq - mean)*scale_c*qw + qb ----------
__global__ void k_pass3_q(const unsigned char* __restrict__ qc,
                          const float* __restrict__ P,
                          float* __restrict__ out) {
    const int p = blockIdx.x, c = p & 63;
    const float scale = P[0], zp = P[1];
    const float sc = P[2 + c], qw = P[66 + c], qb = P[130 + c], mn = P[194 + c];
    const uchar4* qp = (const uchar4*)qc + (size_t)p * F4PP;
    float4* op = (float4*)out + (size_t)p * F4PP;
#pragma unroll
    for (int i = 0; i < 16; ++i) {
        const int idx = threadIdx.x + i * 256;
        uchar4 u = qp[idx];
        float4 o;
        o.x = (((float)u.x - zp) * scale - mn) * sc * qw + qb;
        o.y = (((float)u.y - zp) * scale - mn) * sc * qw + qb;
        o.z = (((float)u.z - zp) * scale - mn) * sc * qw + qb;
        o.w = (((float)u.w - zp) * scale - mn) * sc * qw + qb;
        op[idx] = o;
    }
}

__global__ void k_pass3_x(const float* __restrict__ x,
                          const float* __restrict__ P,
                          float* __restrict__ out) {
    const int p = blockIdx.x, c = p & 63;
    const float scale = P[0], zp = P[1];
    const float sc = P[2 + c], qw = P[66 + c], qb = P[130 + c], mn = P[194 + c];
    const float4* xp = (const float4*)x + (size_t)p * F4PP;
    float4* op = (float4*)out + (size_t)p * F4PP;
#pragma unroll
    for (int i = 0; i < 16; ++i) {
        const int idx = threadIdx.x + i * 256;
        float4 v = xp[idx];
        float4 o;
        o.x = (quantv(v.x, scale, zp) - mn) * sc * qw + qb;
        o.y = (quantv(v.y, scale, zp) - mn) * sc * qw + qb;
        o.z = (quantv(v.z, scale, zp) - mn) * sc * qw + qb;
        o.w = (quantv(v.w, scale, zp) - mn) * sc * qw + qb;
        op[idx] = o;
    }
}

extern "C" void kernel_launch(void* const* d_in, const int* in_sizes, int n_in,
                              void* d_out, int out_size, void* d_ws, size_t ws_size,
                              hipStream_t stream) {
    const float* x = (const float*)d_in[0];
    const float* w = (const float*)d_in[1];
    const float* b = (const float*)d_in[2];
    float* out = (float*)d_out;
    char* ws = (char*)d_ws;

    unsigned* minEnc = (unsigned*)ws;
    unsigned* maxEnc = (unsigned*)(ws + OFF_MAXENC);
    double*   chSum  = (double*)(ws + OFF_CHSUM);
    float*    P      = (float*)(ws + OFF_P);
    unsigned char* qc = (unsigned char*)(ws + OFF_QC);
    const bool useQ = ws_size >= (size_t)OFF_QC + (size_t)PLANES * HW_;

    // re-init scratch every call (harness does not re-poison between replays)
    hipMemsetAsync(minEnc, 0xFF, OFF_MAXENC, stream);                 // +inf encoded
    hipMemsetAsync(maxEnc, 0x00, (OFF_CHSUM - OFF_MAXENC) + 512, stream); // -inf + chSum=0

    k_pass1<<<PLANES, 256, 0, stream>>>(x, minEnc, maxEnc);
    k_params<<<1, 64, 0, stream>>>(minEnc, maxEnc, w, b, P);
    if (useQ) {
        k_pass2<true><<<PLANES, 256, 0, stream>>>(x, P, chSum, qc);
        k_finalize<<<1, 64, 0, stream>>>(chSum, P);
        k_pass3_q<<<PLANES, 256, 0, stream>>>(qc, P, out);
    } else {
        k_pass2<false><<<PLANES, 256, 0, stream>>>(x, P, chSum, nullptr);
        k_finalize<<<1, 64, 0, stream>>>(chSum, P);
        k_pass3_x<<<PLANES, 256, 0, stream>>>(x, P, out);
    }
}